// Round 2
// baseline (347.387 us; speedup 1.0000x reference)
//
#include <hip/hip_runtime.h>
#include <math.h>

// ---------------------------------------------------------------------------
// CSPN_Propagate — MI355X. Round 2: fused 3-iter CSPN per stage (LDS halo
// tiles) + 4px/thread conv + single prep kernel. 9 dispatches total.
//
// Reference analysis (verified by round-1 pass):
//  * medians/scale/blur_depth_o are dead (rgbd[:,0:1] == rgb ch0).
//  * i==0 sparse substitution in _cspn is a no-op; per-stage "raw" =
//    dep_fusion, and each stage's result directly produces next stage's raw.
//  * gate_k for pixel p = guidance[k] at neighbor n_k; OOB -> 0.
// ---------------------------------------------------------------------------

#define B 16
#define FH 256
#define FW 512
#define TH 32
#define TW 32
#define HALO 3
#define LDIM (TW + 2 * HALO)  // 38

// ------------------------- prep: all raw buffers ----------------------------
// RAW0 (96x192): full gt/blur/rgb fusion. RAW1..3: fill with rgb ch0 at the
// stage crop (ring survives; interior overwritten by the previous stage's
// fused-CSPN epilogue before it is read).
__global__ __launch_bounds__(256) void prep_all_kernel(
    const float* __restrict__ gt, const float* __restrict__ blur,
    const float* __restrict__ rgb, float* __restrict__ r0,
    float* __restrict__ r1, float* __restrict__ r2, float* __restrict__ r3) {
  int idx = blockIdx.x * blockDim.x + threadIdx.x;
  const int n0 = B * 96 * 192, n1 = B * 128 * 256, n2 = B * 160 * 320,
            n3 = B * 192 * 384;
  float* dst;
  int h, w, hs, ws;
  if (idx < n0) {
    dst = r0; h = 96; w = 192; hs = 80; ws = 160;
  } else if (idx < n0 + n1) {
    idx -= n0; dst = r1; h = 128; w = 256; hs = 64; ws = 128;
  } else if (idx < n0 + n1 + n2) {
    idx -= n0 + n1; dst = r2; h = 160; w = 320; hs = 48; ws = 96;
  } else if (idx < n0 + n1 + n2 + n3) {
    idx -= n0 + n1 + n2; dst = r3; h = 192; w = 384; hs = 32; ws = 64;
  } else {
    return;
  }
  int x = idx % w;
  int t = idx / w;
  int y = t % h;
  int b = t / h;
  size_t g = (size_t)b * FH * FW + (size_t)(hs + y) * FW + (ws + x);
  float dep = rgb[((size_t)b * 3) * FH * FW + (size_t)(hs + y) * FW + (ws + x)];
  if (dst == r0) {
    float gv = gt[g];
    float s = gv / blur[g];
    float dl = (s > 1.2f || s < 0.8f) ? 0.0f : gv;
    dst[idx] = (dl > 0.0f) ? dl : dep;
  } else {
    dst[idx] = dep;
  }
}

// --------------------------- conv block + ELU -------------------------------
// 4 consecutive x-pixels per thread; float4 feature loads; float4 guid stores.
__global__ __launch_bounds__(256) void conv_guid_kernel(
    const float* __restrict__ feat, const float* __restrict__ wgt,
    const float* __restrict__ bias, float* __restrict__ guid, int h, int w,
    int hs, int ws) {
  int idx = blockIdx.x * blockDim.x + threadIdx.x;
  int wq = w >> 2;
  int total = B * h * wq;
  if (idx >= total) return;
  int x = (idx % wq) << 2;
  int t = idx / wq;
  int y = t % h;
  int b = t / h;

  int ry[3];
#pragma unroll
  for (int k = 0; k < 3; ++k) {
    int cy = y + k - 1;
    cy = (cy < 0) ? 1 : ((cy >= h) ? (h - 2) : cy);
    ry[k] = hs + cy;
  }
  int xm1 = ws + ((x == 0) ? 1 : x - 1);
  int xp4 = ws + ((x + 4 >= w) ? w - 2 : x + 4);

  float acc[8][4];
#pragma unroll
  for (int o = 0; o < 8; ++o) {
    float bv = bias[o];
#pragma unroll
    for (int p = 0; p < 4; ++p) acc[o][p] = bv;
  }

  const float* fb = feat + (size_t)b * 16 * FH * FW;
  for (int ci = 0; ci < 16; ++ci) {
    const float* fc = fb + (size_t)ci * FH * FW;
#pragma unroll
    for (int ky = 0; ky < 3; ++ky) {
      const float* frow = fc + (size_t)ry[ky] * FW;
      float4 m = *(const float4*)(frow + ws + x);
      float v[6];
      v[0] = frow[xm1];
      v[1] = m.x; v[2] = m.y; v[3] = m.z; v[4] = m.w;
      v[5] = frow[xp4];
#pragma unroll
      for (int o = 0; o < 8; ++o) {
        int wb = ((o * 16 + ci) * 3 + ky) * 3;
        float w0 = wgt[wb + 0], w1 = wgt[wb + 1], w2 = wgt[wb + 2];
#pragma unroll
        for (int p = 0; p < 4; ++p)
          acc[o][p] = fmaf(v[p], w0,
                      fmaf(v[p + 1], w1, fmaf(v[p + 2], w2, acc[o][p])));
      }
    }
  }

  size_t hw = (size_t)h * w;
  float* gb = guid + (size_t)b * 8 * hw + (size_t)y * w + x;
#pragma unroll
  for (int o = 0; o < 8; ++o) {
    float4 r;
    float a0 = acc[o][0], a1 = acc[o][1], a2 = acc[o][2], a3 = acc[o][3];
    r.x = (a0 > 0.0f) ? a0 : expm1f(a0);
    r.y = (a1 > 0.0f) ? a1 : expm1f(a1);
    r.z = (a2 > 0.0f) ? a2 : expm1f(a2);
    r.w = (a3 > 0.0f) ? a3 : expm1f(a3);
    *(float4*)(gb + (size_t)o * hw) = r;
  }
}

// ---------------- fused CSPN x3 + finalize epilogue -------------------------
// One 32x32 output tile per block; stage region 38x38 in LDS.
// iter1 over 36^2, iter2 over 34^2, iter3 over 32^2 (written straight out).
__global__ __launch_bounds__(256) void cspn3_kernel(
    const float* __restrict__ guid, const float* __restrict__ raw,
    const float* __restrict__ rgb, float* __restrict__ dst, int h, int w,
    int hs, int ws, int h2, int w2, int ph, int pw, int last) {
  __shared__ float sg[8][LDIM][LDIM];
  __shared__ float sraw[LDIM][LDIM];
  __shared__ float s0[LDIM][LDIM];
  __shared__ float s1[LDIM][LDIM];

  int tpw = w / TW, tph = h / TH;
  int tile = blockIdx.x;
  int tx = tile % tpw;
  int t2 = tile / tpw;
  int ty = t2 % tph;
  int b = t2 / tph;
  int oy = ty * TH - HALO, ox = tx * TW - HALO;
  int tid = threadIdx.x;

  const float* gb = guid + (size_t)b * 8 * h * w;
  const float* rb = raw + (size_t)b * h * w;

  for (int e = tid; e < LDIM * LDIM; e += 256) {
    int r = e / LDIM, c = e % LDIM;
    int gy = oy + r, gx = ox + c;
    bool in = (gy >= 0 && gy < h && gx >= 0 && gx < w);
    sraw[r][c] = in ? rb[(size_t)gy * w + gx] : 0.0f;
  }
  for (int e = tid; e < 8 * LDIM * LDIM; e += 256) {
    int k = e / (LDIM * LDIM);
    int r = (e / LDIM) % LDIM;
    int c = e % LDIM;
    int gy = oy + r, gx = ox + c;
    bool in = (gy >= 0 && gy < h && gx >= 0 && gx < w);
    sg[k][r][c] = in ? gb[((size_t)k * h + gy) * w + gx] : 0.0f;
  }
  __syncthreads();

  const int dy[8] = {1, 1, 1, 0, 0, -1, -1, -1};
  const int dx[8] = {1, 0, -1, 1, -1, 1, 0, -1};

#define CSPN_ITER(SRC, DST_, DIM, OFF)                                       \
  for (int p = tid; p < (DIM) * (DIM); p += 256) {                           \
    int py = p / (DIM) + (OFF), px = p % (DIM) + (OFF);                      \
    int gy = oy + py, gx = ox + px;                                          \
    float wsum = 0.0f, asum = 0.0f, nsum = 0.0f;                             \
    _Pragma("unroll") for (int k = 0; k < 8; ++k) {                          \
      int ny = py + dy[k], nx = px + dx[k];                                  \
      float g = sg[k][ny][nx];                                               \
      wsum += g;                                                             \
      asum += fabsf(g);                                                      \
      nsum += g * SRC[ny][nx];                                               \
    }                                                                        \
    bool in = (gy >= 0 && gy < h && gx >= 0 && gx < w);                      \
    float inv = 1.0f / asum;                                                 \
    DST_[py][px] =                                                           \
        in ? ((1.0f - wsum * inv) * sraw[py][px] + nsum * inv) : 0.0f;       \
  }

  CSPN_ITER(sraw, s0, TH + 4, 1)
  __syncthreads();
  CSPN_ITER(s0, s1, TH + 2, 2)
  __syncthreads();

  // iter 3 + epilogue (positions are always in-image: tiles cover the image)
  for (int p = tid; p < TH * TW; p += 256) {
    int py = p / TW + HALO, px = p % TW + HALO;
    int gy = oy + py, gx = ox + px;
    float wsum = 0.0f, asum = 0.0f, nsum = 0.0f;
#pragma unroll
    for (int k = 0; k < 8; ++k) {
      int ny = py + dy[k], nx = px + dx[k];
      float g = sg[k][ny][nx];
      wsum += g;
      asum += fabsf(g);
      nsum += g * s1[ny][nx];
    }
    float inv = 1.0f / asum;
    float val = (1.0f - wsum * inv) * sraw[py][px] + nsum * inv;
    float dl = fminf(fmaxf(val, 0.0f), 1.0f);
    if (last) {
      dst[((size_t)b * h + gy) * w + gx] = dl;
    } else {
      float dep =
          rgb[((size_t)b * 3) * FH * FW + (size_t)(hs + gy) * FW + (ws + gx)];
      dst[((size_t)b * h2 + (gy + ph)) * w2 + (gx + pw)] =
          (dl > 0.0f) ? dl : dep;
    }
  }
#undef CSPN_ITER
}

// ---------------------------------------------------------------------------
extern "C" void kernel_launch(void* const* d_in, const int* in_sizes, int n_in,
                              void* d_out, int out_size, void* d_ws,
                              size_t ws_size, hipStream_t stream) {
  (void)in_sizes; (void)n_in; (void)out_size; (void)ws_size;
  const float* feat = (const float*)d_in[0];
  const float* blur = (const float*)d_in[1];
  const float* gt = (const float*)d_in[2];
  const float* rgb = (const float*)d_in[3];
  const float* W[4] = {(const float*)d_in[5], (const float*)d_in[7],
                       (const float*)d_in[9], (const float*)d_in[11]};
  const float* Bs[4] = {(const float*)d_in[6], (const float*)d_in[8],
                        (const float*)d_in[10], (const float*)d_in[12]};
  float* out = (float*)d_out;

  // workspace layout (floats)
  float* GUID = (float*)d_ws;                       // 16*8*192*384
  float* RAW[4];
  RAW[0] = GUID + (size_t)B * 8 * 192 * 384;        // 96*192
  RAW[1] = RAW[0] + (size_t)B * 96 * 192;           // 128*256
  RAW[2] = RAW[1] + (size_t)B * 128 * 256;          // 160*320
  RAW[3] = RAW[2] + (size_t)B * 160 * 320;          // 192*384

  const int CH[4] = {96, 128, 160, 192};
  const int CW[4] = {192, 256, 320, 384};

  {
    int n = B * (96 * 192 + 128 * 256 + 160 * 320 + 192 * 384);
    prep_all_kernel<<<(n + 255) / 256, 256, 0, stream>>>(gt, blur, rgb, RAW[0],
                                                         RAW[1], RAW[2],
                                                         RAW[3]);
  }

  for (int i = 0; i < 4; ++i) {
    int h = CH[i], w = CW[i];
    int hs = (FH - h) / 2, ws = (FW - w) / 2;

    int nconv = B * h * (w >> 2);
    conv_guid_kernel<<<(nconv + 255) / 256, 256, 0, stream>>>(
        feat, W[i], Bs[i], GUID, h, w, hs, ws);

    int ntiles = B * (h / TH) * (w / TW);
    if (i < 3) {
      int h2 = CH[i + 1], w2 = CW[i + 1];
      int ph = (h2 - h) / 2, pw = (w2 - w) / 2;
      cspn3_kernel<<<ntiles, 256, 0, stream>>>(GUID, RAW[i], rgb, RAW[i + 1],
                                               h, w, hs, ws, h2, w2, ph, pw,
                                               0);
    } else {
      cspn3_kernel<<<ntiles, 256, 0, stream>>>(GUID, RAW[i], rgb, out, h, w,
                                               hs, ws, h, w, 0, 0, 1);
    }
  }
}

// Round 4
// 191.537 us; speedup vs baseline: 1.8137x; 1.8137x over previous
//
#include <hip/hip_runtime.h>
#include <math.h>

// ---------------------------------------------------------------------------
// CSPN_Propagate — MI355X. Round 4:
//  * gates fp32 planar (round-3's bf16 gates lost 0.34 absmax: intermediate
//    CSPN values reach ~7, so 0.4% gate error compounds past threshold).
//  * cspn3: gates gathered from GLOBAL (L3-resident) + normalized ONCE into
//    registers; 3 iterations in LDS ping-pong (17.3 KB only) + fused epilogue.
//  * all 4 convs in one dispatch (fp32 VALU, float4 loads/stores).
//  * 6 dispatches total.
// ---------------------------------------------------------------------------

#define B 16
#define FH 256
#define FW 512
#define TH 32
#define TW 32
#define HALO 3
#define LD 38
#define GD 36
#define MAXC 6

// ------------------------- prep: all raw buffers ----------------------------
__global__ __launch_bounds__(256) void prep_all_kernel(
    const float* __restrict__ gt, const float* __restrict__ blur,
    const float* __restrict__ rgb, float* __restrict__ r0,
    float* __restrict__ r1, float* __restrict__ r2, float* __restrict__ r3) {
  int idx = blockIdx.x * blockDim.x + threadIdx.x;
  const int n0 = B * 96 * 192, n1 = B * 128 * 256, n2 = B * 160 * 320,
            n3 = B * 192 * 384;
  float* dst;
  int h, w, hs, ws;
  if (idx < n0) {
    dst = r0; h = 96; w = 192; hs = 80; ws = 160;
  } else if (idx < n0 + n1) {
    idx -= n0; dst = r1; h = 128; w = 256; hs = 64; ws = 128;
  } else if (idx < n0 + n1 + n2) {
    idx -= n0 + n1; dst = r2; h = 160; w = 320; hs = 48; ws = 96;
  } else if (idx < n0 + n1 + n2 + n3) {
    idx -= n0 + n1 + n2; dst = r3; h = 192; w = 384; hs = 32; ws = 64;
  } else {
    return;
  }
  int x = idx % w;
  int t = idx / w;
  int y = t % h;
  int b = t / h;
  size_t g = (size_t)b * FH * FW + (size_t)(hs + y) * FW + (ws + x);
  float dep = rgb[((size_t)b * 3) * FH * FW + (size_t)(hs + y) * FW + (ws + x)];
  if (dst == r0) {
    float gv = gt[g];
    float s = gv / blur[g];
    float dl = (s > 1.2f || s < 0.8f) ? 0.0f : gv;
    dst[idx] = (dl > 0.0f) ? dl : dep;
  } else {
    dst[idx] = dep;
  }
}

// ------------------- conv block + ELU, all 4 stages, one dispatch -----------
// 4 px/thread, float4 feature loads, planar fp32 float4 guid stores.
__global__ __launch_bounds__(256) void conv_all_kernel(
    const float* __restrict__ feat, const float* __restrict__ w0c,
    const float* __restrict__ b0c, float* __restrict__ g0,
    const float* __restrict__ w1c, const float* __restrict__ b1c,
    float* __restrict__ g1, const float* __restrict__ w2c,
    const float* __restrict__ b2c, float* __restrict__ g2,
    const float* __restrict__ w3c, const float* __restrict__ b3c,
    float* __restrict__ g3) {
  int bid = blockIdx.x;
  int h, w, base;
  const float *wgt, *bias;
  float* guid;
  if (bid < 288)       { h = 96;  w = 192; wgt = w0c; bias = b0c; guid = g0; base = 0; }
  else if (bid < 800)  { h = 128; w = 256; wgt = w1c; bias = b1c; guid = g1; base = 288; }
  else if (bid < 1600) { h = 160; w = 320; wgt = w2c; bias = b2c; guid = g2; base = 800; }
  else                 { h = 192; w = 384; wgt = w3c; bias = b3c; guid = g3; base = 1600; }
  int hs = (FH - h) >> 1, wss = (FW - w) >> 1;
  int idx = (bid - base) * 256 + threadIdx.x;
  int wq = w >> 2;
  int x = (idx % wq) << 2;
  int t = idx / wq;
  int y = t % h;
  int b = t / h;

  int ry[3];
#pragma unroll
  for (int k = 0; k < 3; ++k) {
    int cy = y + k - 1;
    cy = (cy < 0) ? 1 : ((cy >= h) ? (h - 2) : cy);
    ry[k] = hs + cy;
  }
  int xm1 = wss + ((x == 0) ? 1 : x - 1);
  int xp4 = wss + ((x + 4 >= w) ? w - 2 : x + 4);

  float acc[8][4];
#pragma unroll
  for (int o = 0; o < 8; ++o) {
    float bv = bias[o];
#pragma unroll
    for (int p = 0; p < 4; ++p) acc[o][p] = bv;
  }

  const float* fb = feat + (size_t)b * 16 * FH * FW;
  for (int ci = 0; ci < 16; ++ci) {
    const float* fc = fb + (size_t)ci * FH * FW;
#pragma unroll
    for (int ky = 0; ky < 3; ++ky) {
      const float* frow = fc + (size_t)ry[ky] * FW;
      float4 m = *(const float4*)(frow + wss + x);
      float v[6];
      v[0] = frow[xm1];
      v[1] = m.x; v[2] = m.y; v[3] = m.z; v[4] = m.w;
      v[5] = frow[xp4];
#pragma unroll
      for (int o = 0; o < 8; ++o) {
        int wb = ((o * 16 + ci) * 3 + ky) * 3;
        float w0 = wgt[wb + 0], w1 = wgt[wb + 1], w2 = wgt[wb + 2];
#pragma unroll
        for (int p = 0; p < 4; ++p)
          acc[o][p] = fmaf(v[p], w0,
                      fmaf(v[p + 1], w1, fmaf(v[p + 2], w2, acc[o][p])));
      }
    }
  }

  size_t hw = (size_t)h * w;
  float* gb = guid + (size_t)b * 8 * hw + (size_t)y * w + x;
#pragma unroll
  for (int o = 0; o < 8; ++o) {
    float4 r;
    float a0 = acc[o][0], a1 = acc[o][1], a2 = acc[o][2], a3 = acc[o][3];
    r.x = (a0 > 0.0f) ? a0 : expm1f(a0);
    r.y = (a1 > 0.0f) ? a1 : expm1f(a1);
    r.z = (a2 > 0.0f) ? a2 : expm1f(a2);
    r.w = (a3 > 0.0f) ? a3 : expm1f(a3);
    *(float4*)(gb + (size_t)o * hw) = r;
  }
}

// ---------------- fused CSPN x3 with register gates -------------------------
// LDS: raw + 2 ping-pong buffers only (17.3 KB). Gates gathered per-thread
// from global planar guid (L3-resident), normalized once, kept in VGPRs.
__global__ __launch_bounds__(256) void cspn3_kernel(
    const float* __restrict__ guid, const float* __restrict__ raw,
    const float* __restrict__ rgb, float* __restrict__ dst, int h, int w,
    int hs, int wss, int h2, int w2, int ph, int pw, int last) {
  __shared__ float sraw[LD * LD];
  __shared__ float s0[LD * LD];
  __shared__ float s1[LD * LD];

  int tpw = w / TW, tph = h / TH;
  int tile = blockIdx.x;
  int tx = tile % tpw;
  int t2 = tile / tpw;
  int ty = t2 % tph;
  int b = t2 / tph;
  int oy = ty * TH - HALO, ox = tx * TW - HALO;
  int tid = threadIdx.x;

  const float* rb = raw + (size_t)b * h * w;

  // ---- stage raw (38x38) ----
  for (int e = tid; e < LD * LD; e += 256) {
    int r = e / LD, c = e % LD;
    int gy = oy + r, gx = ox + c;
    bool in = (gy >= 0 && gy < h && gx >= 0 && gx < w);
    sraw[e] = in ? rb[(size_t)gy * w + gx] : 0.0f;
  }
  __syncthreads();

  const int dy8[8] = {1, 1, 1, 0, 0, -1, -1, -1};
  const int dx8[8] = {1, 0, -1, 1, -1, 1, 0, -1};
  const int off8[8] = {LD + 1, LD, LD - 1, 1, -1, -LD + 1, -LD, -LD - 1};

  // ---- gather gates from global + normalize into registers (once) ----
  const float* gb = guid + (size_t)b * 8 * h * w;
  float cg[MAXC][8];
  float r0[MAXC];
  int adr[MAXC];
#pragma unroll
  for (int ch = 0; ch < MAXC; ++ch) {
    int p = tid + ch * 256;
    bool ok = p < GD * GD;
    int pp = ok ? p : 0;
    int py = pp / GD + 1, px = pp % GD + 1;
    adr[ch] = py * LD + px;
    int gy = oy + py, gx = ox + px;
    bool in = ok && gy >= 0 && gy < h && gx >= 0 && gx < w;
    float wsum = 0.0f, asum = 0.0f;
    float g[8];
#pragma unroll
    for (int k = 0; k < 8; ++k) {
      int ny = gy + dy8[k], nx = gx + dx8[k];
      bool nin = ok && ny >= 0 && ny < h && nx >= 0 && nx < w;
      float gk = nin ? gb[(size_t)k * h * w + (size_t)ny * w + nx] : 0.0f;
      g[k] = gk;
      wsum += gk;
      asum += fabsf(gk);
    }
    float inv = in ? (1.0f / asum) : 0.0f;
#pragma unroll
    for (int k = 0; k < 8; ++k) cg[ch][k] = g[k] * inv;
    r0[ch] = in ? (1.0f - wsum * inv) * sraw[adr[ch]] : 0.0f;
  }

  // ---- iter 1: sraw -> s0 over 36x36 (OOB-image px get 0 via r0/cg=0) ----
#pragma unroll
  for (int ch = 0; ch < MAXC; ++ch) {
    int p = tid + ch * 256;
    if (p < GD * GD) {
      float v = r0[ch];
#pragma unroll
      for (int k = 0; k < 8; ++k) v += cg[ch][k] * sraw[adr[ch] + off8[k]];
      s0[adr[ch]] = v;
    }
  }
  __syncthreads();

  // ---- iter 2: s0 -> s1 over [2,35]^2 ----
#pragma unroll
  for (int ch = 0; ch < MAXC; ++ch) {
    int p = tid + ch * 256;
    if (p < GD * GD) {
      int py = p / GD + 1, px = p % GD + 1;
      if (py >= 2 && py <= 35 && px >= 2 && px <= 35) {
        float v = r0[ch];
#pragma unroll
        for (int k = 0; k < 8; ++k) v += cg[ch][k] * s0[adr[ch] + off8[k]];
        s1[adr[ch]] = v;
      }
    }
  }
  __syncthreads();

  // ---- iter 3 + epilogue over the 32x32 core (always in-image) ----
#pragma unroll
  for (int ch = 0; ch < MAXC; ++ch) {
    int p = tid + ch * 256;
    if (p < GD * GD) {
      int py = p / GD + 1, px = p % GD + 1;
      if (py >= 3 && py <= 34 && px >= 3 && px <= 34) {
        float v = r0[ch];
#pragma unroll
        for (int k = 0; k < 8; ++k) v += cg[ch][k] * s1[adr[ch] + off8[k]];
        float dl = fminf(fmaxf(v, 0.0f), 1.0f);
        int gy = oy + py, gx = ox + px;
        if (last) {
          dst[((size_t)b * h + gy) * w + gx] = dl;
        } else {
          float dep = rgb[((size_t)b * 3) * FH * FW + (size_t)(hs + gy) * FW +
                          (wss + gx)];
          dst[((size_t)b * h2 + (gy + ph)) * w2 + (gx + pw)] =
              (dl > 0.0f) ? dl : dep;
        }
      }
    }
  }
}

// ---------------------------------------------------------------------------
extern "C" void kernel_launch(void* const* d_in, const int* in_sizes, int n_in,
                              void* d_out, int out_size, void* d_ws,
                              size_t ws_size, hipStream_t stream) {
  (void)in_sizes; (void)n_in; (void)out_size; (void)ws_size;
  const float* feat = (const float*)d_in[0];
  const float* blur = (const float*)d_in[1];
  const float* gt = (const float*)d_in[2];
  const float* rgb = (const float*)d_in[3];
  const float* W[4] = {(const float*)d_in[5], (const float*)d_in[7],
                       (const float*)d_in[9], (const float*)d_in[11]};
  const float* Bs[4] = {(const float*)d_in[6], (const float*)d_in[8],
                        (const float*)d_in[10], (const float*)d_in[12]};
  float* out = (float*)d_out;

  // workspace layout (floats): 4 planar fp32 guid buffers + 4 raw buffers
  float* G0 = (float*)d_ws;
  float* G1 = G0 + (size_t)B * 8 * 96 * 192;
  float* G2 = G1 + (size_t)B * 8 * 128 * 256;
  float* G3 = G2 + (size_t)B * 8 * 160 * 320;
  float* RAW[4];
  RAW[0] = G3 + (size_t)B * 8 * 192 * 384;
  RAW[1] = RAW[0] + (size_t)B * 96 * 192;
  RAW[2] = RAW[1] + (size_t)B * 128 * 256;
  RAW[3] = RAW[2] + (size_t)B * 160 * 320;
  float* G[4] = {G0, G1, G2, G3};

  const int CH[4] = {96, 128, 160, 192};
  const int CW[4] = {192, 256, 320, 384};

  {
    int n = B * (96 * 192 + 128 * 256 + 160 * 320 + 192 * 384);
    prep_all_kernel<<<(n + 255) / 256, 256, 0, stream>>>(gt, blur, rgb, RAW[0],
                                                         RAW[1], RAW[2],
                                                         RAW[3]);
  }

  conv_all_kernel<<<2752, 256, 0, stream>>>(feat, W[0], Bs[0], G0, W[1], Bs[1],
                                            G1, W[2], Bs[2], G2, W[3], Bs[3],
                                            G3);

  for (int i = 0; i < 4; ++i) {
    int h = CH[i], w = CW[i];
    int hs = (FH - h) / 2, wss = (FW - w) / 2;
    int ntiles = B * (h / TH) * (w / TW);
    if (i < 3) {
      int h2 = CH[i + 1], w2 = CW[i + 1];
      int ph = (h2 - h) / 2, pw = (w2 - w) / 2;
      cspn3_kernel<<<ntiles, 256, 0, stream>>>(G[i], RAW[i], rgb, RAW[i + 1],
                                               h, w, hs, wss, h2, w2, ph, pw,
                                               0);
    } else {
      cspn3_kernel<<<ntiles, 256, 0, stream>>>(G[i], RAW[i], rgb, out, h, w,
                                               hs, wss, h, w, 0, 0, 1);
    }
  }
}